// Round 1
// baseline (917.473 us; speedup 1.0000x reference)
//
#include <hip/hip_runtime.h>
#include <math.h>

#define C_DIM 256
#define N_DIM 4096

// ---------------------------------------------------------------------------
// GEMM: Y[b,o,n] = sum_c W[o,c] * X[b,c,n] + bias[o]  (+ res[b,o,n] if res)
// W: [256,256] row-major. X,Y,res: [B, C, N] with N contiguous.
// 64x64 tile, BK=16, 256 threads, 4x4 micro-tile per thread.
// ---------------------------------------------------------------------------
__global__ __launch_bounds__(256) void gemm_proj(
    const float* __restrict__ W, const float* __restrict__ bias,
    const float* __restrict__ X, const float* __restrict__ res,
    float* __restrict__ Y)
{
    const int n0 = blockIdx.x * 64;
    const int o0 = blockIdx.y * 64;
    const int b  = blockIdx.z;
    const size_t bofs = (size_t)b * C_DIM * N_DIM;
    const float* Xb = X + bofs;
    float* Yb = Y + bofs;

    __shared__ float Ws[16][68];   // [k][o_local], stride 68 (16B-aligned, 2-way banks)
    __shared__ float Xs[16][64];   // [k][n_local]

    const int t  = threadIdx.x;
    const int tx = t & 15;         // n micro-tile
    const int ty = t >> 4;         // o micro-tile
    const int w_or = t >> 2;       // 0..63 row of W tile
    const int w_cg = t & 3;        // float4 col group of W tile
    const int x_cr = t >> 4;       // 0..15 row of X tile
    const int x_ng = t & 15;       // float4 col group of X tile

    float acc[4][4];
#pragma unroll
    for (int i = 0; i < 4; ++i)
#pragma unroll
        for (int j = 0; j < 4; ++j) acc[i][j] = 0.f;

    for (int c0 = 0; c0 < C_DIM; c0 += 16) {
        float4 wv = *(const float4*)&W[(size_t)(o0 + w_or) * C_DIM + c0 + 4 * w_cg];
        float4 xv = *(const float4*)&Xb[(size_t)(c0 + x_cr) * N_DIM + n0 + 4 * x_ng];
        __syncthreads();   // protect previous iteration's LDS reads
        Ws[4 * w_cg + 0][w_or] = wv.x;
        Ws[4 * w_cg + 1][w_or] = wv.y;
        Ws[4 * w_cg + 2][w_or] = wv.z;
        Ws[4 * w_cg + 3][w_or] = wv.w;
        *(float4*)&Xs[x_cr][4 * x_ng] = xv;
        __syncthreads();
#pragma unroll
        for (int kk = 0; kk < 16; ++kk) {
            float4 av = *(const float4*)&Ws[kk][4 * ty];
            float4 bv = *(const float4*)&Xs[kk][4 * tx];
            float a[4]  = {av.x, av.y, av.z, av.w};
            float bb[4] = {bv.x, bv.y, bv.z, bv.w};
#pragma unroll
            for (int i = 0; i < 4; ++i)
#pragma unroll
                for (int j = 0; j < 4; ++j)
                    acc[i][j] = fmaf(a[i], bb[j], acc[i][j]);
        }
    }

#pragma unroll
    for (int i = 0; i < 4; ++i) {
        const int o = o0 + 4 * ty + i;
        const float bi = bias[o];
        float4 v;
        v.x = acc[i][0] + bi; v.y = acc[i][1] + bi;
        v.z = acc[i][2] + bi; v.w = acc[i][3] + bi;
        if (res != nullptr) {
            float4 rv = *(const float4*)&res[bofs + (size_t)o * N_DIM + n0 + 4 * tx];
            v.x += rv.x; v.y += rv.y; v.z += rv.z; v.w += rv.w;
        }
        *(float4*)&Yb[(size_t)o * N_DIM + n0 + 4 * tx] = v;
    }
}

// ---------------------------------------------------------------------------
// Flash attention, fp32. Qp/Kp/Vp: [B, C, N], head h uses channels h*32..+32.
// Block = (32-query tile, head, batch); 256 threads: thread = (qi = t>>3, kg = t&7).
// Each thread owns keys 8*kg..+8 of the 64-key tile; row reductions are
// shuffles within the 8-lane kg group (qi groups never straddle a wave).
// Writes AO in-place over Qp (block reads exactly the slice it writes).
// ---------------------------------------------------------------------------
__global__ __launch_bounds__(256) void flash_attn(
    const float* __restrict__ Qp, const float* __restrict__ Kp,
    const float* __restrict__ Vp, float* __restrict__ AO)
{
    const int n0 = blockIdx.x * 32;
    const int h  = blockIdx.y;
    const int b  = blockIdx.z;
    const size_t base = ((size_t)b * C_DIM + (size_t)h * 32) * N_DIM;
    const float* Qb = Qp + base;
    const float* Kb = Kp + base;
    const float* Vb = Vp + base;

    __shared__ float Qs[32][32];   // [cd][qi]
    __shared__ float Ks[32][64];   // [cd][k]
    __shared__ float Vs[32][64];   // [cd][k]

    const int t  = threadIdx.x;
    const int qi = t >> 3;
    const int kg = t & 7;

    {   // stage Q tile (natural layout, coalesced float4)
        const int row = t >> 3, f4 = t & 7;
        *(float4*)&Qs[row][4 * f4] =
            *(const float4*)&Qb[(size_t)row * N_DIM + n0 + 4 * f4];
    }

    float m_i = -INFINITY, l_i = 0.f;
    float Oacc[32];
#pragma unroll
    for (int c = 0; c < 32; ++c) Oacc[c] = 0.f;

    const float scale = 0.17677669529663687f;  // 1/sqrt(32)
    const int krow = t >> 4, kf4 = t & 15;

    for (int k0 = 0; k0 < N_DIM; k0 += 64) {
        __syncthreads();   // previous tile's reads done
        *(float4*)&Ks[krow][4 * kf4] =
            *(const float4*)&Kb[(size_t)krow * N_DIM + k0 + 4 * kf4];
        *(float4*)&Ks[krow + 16][4 * kf4] =
            *(const float4*)&Kb[(size_t)(krow + 16) * N_DIM + k0 + 4 * kf4];
        *(float4*)&Vs[krow][4 * kf4] =
            *(const float4*)&Vb[(size_t)krow * N_DIM + k0 + 4 * kf4];
        *(float4*)&Vs[krow + 16][4 * kf4] =
            *(const float4*)&Vb[(size_t)(krow + 16) * N_DIM + k0 + 4 * kf4];
        __syncthreads();

        // S = Q . K^T for my 8 keys
        float s[8];
#pragma unroll
        for (int j = 0; j < 8; ++j) s[j] = 0.f;
#pragma unroll
        for (int cd = 0; cd < 32; ++cd) {
            const float q = Qs[cd][qi];
            float4 ka  = *(const float4*)&Ks[cd][8 * kg];
            float4 kb2 = *(const float4*)&Ks[cd][8 * kg + 4];
            s[0] = fmaf(q, ka.x,  s[0]);
            s[1] = fmaf(q, ka.y,  s[1]);
            s[2] = fmaf(q, ka.z,  s[2]);
            s[3] = fmaf(q, ka.w,  s[3]);
            s[4] = fmaf(q, kb2.x, s[4]);
            s[5] = fmaf(q, kb2.y, s[5]);
            s[6] = fmaf(q, kb2.z, s[6]);
            s[7] = fmaf(q, kb2.w, s[7]);
        }

        // online softmax
        float mt = -INFINITY;
#pragma unroll
        for (int j = 0; j < 8; ++j) { s[j] *= scale; mt = fmaxf(mt, s[j]); }
        mt = fmaxf(mt, __shfl_xor(mt, 1, 64));
        mt = fmaxf(mt, __shfl_xor(mt, 2, 64));
        mt = fmaxf(mt, __shfl_xor(mt, 4, 64));
        const float m_new = fmaxf(m_i, mt);
        const float alpha = __expf(m_i - m_new);   // first iter: exp(-inf)=0
        float p[8], lsum = 0.f;
#pragma unroll
        for (int j = 0; j < 8; ++j) { p[j] = __expf(s[j] - m_new); lsum += p[j]; }
        lsum += __shfl_xor(lsum, 1, 64);
        lsum += __shfl_xor(lsum, 2, 64);
        lsum += __shfl_xor(lsum, 4, 64);
        l_i = l_i * alpha + lsum;
        m_i = m_new;

        // O += P . V (partial over my 8 keys)
#pragma unroll
        for (int cd = 0; cd < 32; ++cd) {
            float4 va  = *(const float4*)&Vs[cd][8 * kg];
            float4 vb2 = *(const float4*)&Vs[cd][8 * kg + 4];
            float o = Oacc[cd] * alpha;
            o = fmaf(p[0], va.x,  o);
            o = fmaf(p[1], va.y,  o);
            o = fmaf(p[2], va.z,  o);
            o = fmaf(p[3], va.w,  o);
            o = fmaf(p[4], vb2.x, o);
            o = fmaf(p[5], vb2.y, o);
            o = fmaf(p[6], vb2.z, o);
            o = fmaf(p[7], vb2.w, o);
            Oacc[cd] = o;
        }
    }

    // reduce O partials across the 8 kg threads (butterfly -> all have total)
#pragma unroll
    for (int cd = 0; cd < 32; ++cd) {
        Oacc[cd] += __shfl_xor(Oacc[cd], 1, 64);
        Oacc[cd] += __shfl_xor(Oacc[cd], 2, 64);
        Oacc[cd] += __shfl_xor(Oacc[cd], 4, 64);
    }
    const float rl = 1.f / l_i;
#pragma unroll
    for (int u = 0; u < 4; ++u) {
        const int cd = 4 * kg + u;
        AO[base + (size_t)cd * N_DIM + n0 + qi] = Oacc[cd] * rl;
    }
}

// ---------------------------------------------------------------------------
// GroupNorm over [B, C, N]: group g = channels 8g..8g+8, 32768 elems/group.
// One block per (g, b). Two-pass: stats then normalize.
// ---------------------------------------------------------------------------
__global__ __launch_bounds__(256) void groupnorm_kernel(
    const float* __restrict__ Yv, const float* __restrict__ gw,
    const float* __restrict__ gb, float* __restrict__ out)
{
    const int g = blockIdx.x;
    const int b = blockIdx.y;
    const size_t base = ((size_t)b * C_DIM + (size_t)g * 8) * N_DIM;
    const float4* Y4 = (const float4*)(Yv + base);
    float4* O4 = (float4*)(out + base);
    const int t = threadIdx.x;

    float sum = 0.f, sumsq = 0.f;
    for (int i = t; i < 8192; i += 256) {
        float4 v = Y4[i];
        sum   += v.x + v.y + v.z + v.w;
        sumsq += v.x * v.x + v.y * v.y + v.z * v.z + v.w * v.w;
    }
#pragma unroll
    for (int off = 1; off < 64; off <<= 1) {
        sum   += __shfl_xor(sum, off, 64);
        sumsq += __shfl_xor(sumsq, off, 64);
    }
    __shared__ float red[10];
    const int wid = t >> 6;
    if ((t & 63) == 0) { red[wid] = sum; red[4 + wid] = sumsq; }
    __syncthreads();
    if (t == 0) {
        float s = red[0] + red[1] + red[2] + red[3];
        float q = red[4] + red[5] + red[6] + red[7];
        float mean = s * (1.f / 32768.f);
        float var  = q * (1.f / 32768.f) - mean * mean;
        red[8] = mean;
        red[9] = rsqrtf(var + 1e-5f);
    }
    __syncthreads();
    const float mean = red[8], rstd = red[9];
    for (int i = t; i < 8192; i += 256) {
        const int c = i >> 10;              // 1024 float4 per channel
        const float w   = gw[g * 8 + c] * rstd;
        const float bb2 = gb[g * 8 + c];
        float4 v = Y4[i];
        float4 r;
        r.x = (v.x - mean) * w + bb2;
        r.y = (v.y - mean) * w + bb2;
        r.z = (v.z - mean) * w + bb2;
        r.w = (v.w - mean) * w + bb2;
        O4[i] = r;
    }
}

// ---------------------------------------------------------------------------
extern "C" void kernel_launch(void* const* d_in, const int* in_sizes, int n_in,
                              void* d_out, int out_size, void* d_ws, size_t ws_size,
                              hipStream_t stream)
{
    const float* query = (const float*)d_in[0];
    const float* key   = (const float*)d_in[1];
    const float* q_w   = (const float*)d_in[2];
    const float* q_b   = (const float*)d_in[3];
    const float* k_w   = (const float*)d_in[4];
    const float* k_b   = (const float*)d_in[5];
    const float* v_w   = (const float*)d_in[6];
    const float* v_b   = (const float*)d_in[7];
    const float* o_w   = (const float*)d_in[8];
    const float* o_b   = (const float*)d_in[9];
    const float* gn_w  = (const float*)d_in[10];
    const float* gn_b  = (const float*)d_in[11];

    float* ws = (float*)d_ws;
    const size_t PLANE = (size_t)2 * C_DIM * N_DIM;   // 2M floats per [B,C,N] buffer
    float* Qp = ws;              // Q projection; attention output overwrites in-place
    float* Kp = ws + PLANE;      // K projection; then y = proj + residual buffer
    float* Vp = ws + 2 * PLANE;  // V projection
    // total ws use: 24 MiB

    dim3 gemm_grid(N_DIM / 64, C_DIM / 64, 2);
    gemm_proj<<<gemm_grid, 256, 0, stream>>>(q_w, q_b, query, nullptr, Qp);
    gemm_proj<<<gemm_grid, 256, 0, stream>>>(k_w, k_b, key,   nullptr, Kp);
    gemm_proj<<<gemm_grid, 256, 0, stream>>>(v_w, v_b, key,   nullptr, Vp);

    flash_attn<<<dim3(N_DIM / 32, 8, 2), 256, 0, stream>>>(Qp, Kp, Vp, Qp);

    // proj + bias + residual -> Kp (K projection is dead now)
    gemm_proj<<<gemm_grid, 256, 0, stream>>>(o_w, o_b, Qp, query, Kp);

    groupnorm_kernel<<<dim3(32, 2), 256, 0, stream>>>(Kp, gn_w, gn_b, (float*)d_out);
}

// Round 2
// 318.438 us; speedup vs baseline: 2.8812x; 2.8812x over previous
//
#include <hip/hip_runtime.h>
#include <math.h>

#define C_DIM 256
#define N_DIM 4096

using bf16x8 = __attribute__((ext_vector_type(8))) short;   // 8 bf16 = 4 VGPRs
using f32x16 = __attribute__((ext_vector_type(16))) float;  // 32x32 MFMA acc

__device__ __forceinline__ unsigned pack_bf16_pair(float a, float b) {
    // round-half-up bf16 pack: (lo=a, hi=b)
    unsigned ua = __float_as_uint(a) + 0x8000u;
    unsigned ub = __float_as_uint(b) + 0x8000u;
    return (ua >> 16) | (ub & 0xFFFF0000u);
}
__device__ __forceinline__ short f32_to_bf16(float a) {
    return (short)((__float_as_uint(a) + 0x8000u) >> 16);
}
__device__ __forceinline__ float bf16_to_f32(unsigned short u) {
    return __uint_as_float(((unsigned)u) << 16);
}

// ---------------------------------------------------------------------------
// GEMM: Y[b,o,n] = outscale * (sum_c W[o,c] * X[b,c,n] + bias[o]) (+ res)
// Templated on bf16 input plane / bf16 output plane.
// ---------------------------------------------------------------------------
template <bool IN_BF16, bool OUT_BF16>
__global__ __launch_bounds__(256) void gemm_proj(
    const float* __restrict__ W, const float* __restrict__ bias,
    const void* __restrict__ Xv, const float* __restrict__ res,
    void* __restrict__ Yv, float outscale)
{
    const int n0 = blockIdx.x * 64;
    const int o0 = blockIdx.y * 64;
    const int b  = blockIdx.z;
    const size_t bofs = (size_t)b * C_DIM * N_DIM;

    __shared__ float Ws[16][68];
    __shared__ float Xs[16][64];

    const int t  = threadIdx.x;
    const int tx = t & 15;
    const int ty = t >> 4;
    const int w_or = t >> 2;
    const int w_cg = t & 3;
    const int x_cr = t >> 4;
    const int x_ng = t & 15;

    float acc[4][4];
#pragma unroll
    for (int i = 0; i < 4; ++i)
#pragma unroll
        for (int j = 0; j < 4; ++j) acc[i][j] = 0.f;

    for (int c0 = 0; c0 < C_DIM; c0 += 16) {
        float4 wv = *(const float4*)&W[(size_t)(o0 + w_or) * C_DIM + c0 + 4 * w_cg];
        float4 xv;
        if (IN_BF16) {
            const short* Xb = (const short*)Xv + bofs;
            ushort4 u = *(const ushort4*)&Xb[(size_t)(c0 + x_cr) * N_DIM + n0 + 4 * x_ng];
            xv.x = bf16_to_f32(u.x); xv.y = bf16_to_f32(u.y);
            xv.z = bf16_to_f32(u.z); xv.w = bf16_to_f32(u.w);
        } else {
            const float* Xb = (const float*)Xv + bofs;
            xv = *(const float4*)&Xb[(size_t)(c0 + x_cr) * N_DIM + n0 + 4 * x_ng];
        }
        __syncthreads();
        Ws[4 * w_cg + 0][w_or] = wv.x;
        Ws[4 * w_cg + 1][w_or] = wv.y;
        Ws[4 * w_cg + 2][w_or] = wv.z;
        Ws[4 * w_cg + 3][w_or] = wv.w;
        *(float4*)&Xs[x_cr][4 * x_ng] = xv;
        __syncthreads();
#pragma unroll
        for (int kk = 0; kk < 16; ++kk) {
            float4 av = *(const float4*)&Ws[kk][4 * ty];
            float4 bv = *(const float4*)&Xs[kk][4 * tx];
            float a[4]  = {av.x, av.y, av.z, av.w};
            float bb[4] = {bv.x, bv.y, bv.z, bv.w};
#pragma unroll
            for (int i = 0; i < 4; ++i)
#pragma unroll
                for (int j = 0; j < 4; ++j)
                    acc[i][j] = fmaf(a[i], bb[j], acc[i][j]);
        }
    }

#pragma unroll
    for (int i = 0; i < 4; ++i) {
        const int o = o0 + 4 * ty + i;
        const float bi = bias[o];
        float4 v;
        v.x = acc[i][0] + bi; v.y = acc[i][1] + bi;
        v.z = acc[i][2] + bi; v.w = acc[i][3] + bi;
        if (res != nullptr) {
            float4 rv = *(const float4*)&res[bofs + (size_t)o * N_DIM + n0 + 4 * tx];
            v.x += rv.x; v.y += rv.y; v.z += rv.z; v.w += rv.w;
        }
        v.x *= outscale; v.y *= outscale; v.z *= outscale; v.w *= outscale;
        if (OUT_BF16) {
            short* Yb = (short*)Yv + bofs;
            ushort4 u;
            u.x = (unsigned short)f32_to_bf16(v.x);
            u.y = (unsigned short)f32_to_bf16(v.y);
            u.z = (unsigned short)f32_to_bf16(v.z);
            u.w = (unsigned short)f32_to_bf16(v.w);
            *(ushort4*)&Yb[(size_t)o * N_DIM + n0 + 4 * tx] = u;
        } else {
            float* Yb = (float*)Yv + bofs;
            *(float4*)&Yb[(size_t)o * N_DIM + n0 + 4 * tx] = v;
        }
    }
}

// ---------------------------------------------------------------------------
// MFMA flash attention (bf16, 32x32x16).
// Planes Qp/Kp/Vp/AO: [B, C, N] bf16, head h = channels h*32..+32, d = 32.
// Block = 128 queries x head x batch; 4 waves, each wave owns 32 queries.
// Per 32-key tile:
//   S^T = K . Q^T   (2 MFMAs over d-halves)  -> lane holds 16 keys for q=lane&31
//   online softmax (per-lane rows; 1 shfl_xor(32) to combine half-waves)
//   P -> per-wave LDS (bf16) -> re-read as B-frag
//   O^T = V^T . P^T (2 MFMAs over key-halves), alpha rescale on C regs
// ---------------------------------------------------------------------------
#define PSTR 40   // shorts per LDS row (32 data + 8 pad, 80 B, 16B-aligned)

__global__ __launch_bounds__(256) void flash_mfma(
    const short* __restrict__ Qp, const short* __restrict__ Kp,
    const short* __restrict__ Vp, short* __restrict__ AO)
{
    const int n0 = blockIdx.x * 128;
    const int h  = blockIdx.y;
    const int b  = blockIdx.z;
    const size_t base = ((size_t)b * C_DIM + (size_t)h * 32) * N_DIM;
    const short* Qb = Qp + base;
    const short* Kb = Kp + base;
    const short* Vb = Vp + base;

    __shared__ short KsT[32 * PSTR];     // [key][d]
    __shared__ short Vs[32 * PSTR];      // [d][key]
    __shared__ short Pl[4][32 * PSTR];   // per-wave [q][key]

    const int t    = threadIdx.x;
    const int w    = t >> 6;
    const int lane = t & 63;
    const int q2   = lane >> 5;
    const int l31  = lane & 31;
    const int q    = n0 + w * 32 + l31;   // this lane's query (column of S^T / O^T)

    // Q B-frags: Qf[dh][j] = Q[q][d = dh*16 + q2*8 + j]  (Q pre-scaled in GEMM)
    bf16x8 Qf[2];
#pragma unroll
    for (int dh = 0; dh < 2; ++dh)
#pragma unroll
        for (int j = 0; j < 8; ++j)
            Qf[dh][j] = Qb[(size_t)(dh * 16 + q2 * 8 + j) * N_DIM + q];

    f32x16 Of;
#pragma unroll
    for (int r = 0; r < 16; ++r) Of[r] = 0.f;
    float m_i = -INFINITY, l_i = 0.f;

    const int sd = t >> 3;        // staging: d row 0..31
    const int sk = (t & 7) * 4;   // staging: 4-key group

    short* Pw = &Pl[w][l31 * PSTR];

    for (int k0 = 0; k0 < N_DIM; k0 += 32) {
        ushort4 kv = *(const ushort4*)&Kb[(size_t)sd * N_DIM + k0 + sk];
        ushort4 vv = *(const ushort4*)&Vb[(size_t)sd * N_DIM + k0 + sk];
        __syncthreads();   // previous iteration's K/V frag reads are done
        KsT[(sk + 0) * PSTR + sd] = kv.x;
        KsT[(sk + 1) * PSTR + sd] = kv.y;
        KsT[(sk + 2) * PSTR + sd] = kv.z;
        KsT[(sk + 3) * PSTR + sd] = kv.w;
        *(ushort4*)&Vs[sd * PSTR + sk] = vv;
        __syncthreads();

        // --- S^T = K . Q^T ---
        bf16x8 Kf0 = *(const bf16x8*)&KsT[l31 * PSTR + q2 * 8];        // d 0..15 half
        bf16x8 Kf1 = *(const bf16x8*)&KsT[l31 * PSTR + 16 + q2 * 8];   // d 16..31 half
        f32x16 acc;
#pragma unroll
        for (int r = 0; r < 16; ++r) acc[r] = 0.f;
        acc = __builtin_amdgcn_mfma_f32_32x32x16_bf16(Kf0, Qf[0], acc, 0, 0, 0);
        acc = __builtin_amdgcn_mfma_f32_32x32x16_bf16(Kf1, Qf[1], acc, 0, 0, 0);
        // lane holds S^T[key=(r&3)+8*(r>>2)+4*q2][q=l31], log2-domain (scale folded)

        // --- online softmax (per-lane row q) ---
        float mt = acc[0];
#pragma unroll
        for (int r = 1; r < 16; ++r) mt = fmaxf(mt, acc[r]);
        mt = fmaxf(mt, __shfl_xor(mt, 32, 64));
        const float m_new = fmaxf(m_i, mt);
        float p[16];
        float ls = 0.f;
#pragma unroll
        for (int r = 0; r < 16; ++r) { p[r] = exp2f(acc[r] - m_new); ls += p[r]; }
        ls += __shfl_xor(ls, 32, 64);
        const float alpha = exp2f(m_i - m_new);
        l_i = l_i * alpha + ls;
        m_i = m_new;

        // --- P -> LDS (bf16), keys of reg group g land at 8g + 4*q2 + 0..3 ---
#pragma unroll
        for (int g = 0; g < 4; ++g) {
            uint2 pk;
            pk.x = pack_bf16_pair(p[4 * g + 0], p[4 * g + 1]);
            pk.y = pack_bf16_pair(p[4 * g + 2], p[4 * g + 3]);
            *(uint2*)&Pw[8 * g + 4 * q2] = pk;
        }

        // --- O^T = V^T . P^T with alpha rescale ---
#pragma unroll
        for (int r = 0; r < 16; ++r) Of[r] *= alpha;
        bf16x8 Pf0 = *(const bf16x8*)&Pl[w][l31 * PSTR + q2 * 8];
        bf16x8 Pf1 = *(const bf16x8*)&Pl[w][l31 * PSTR + 16 + q2 * 8];
        bf16x8 Vf0 = *(const bf16x8*)&Vs[l31 * PSTR + q2 * 8];
        bf16x8 Vf1 = *(const bf16x8*)&Vs[l31 * PSTR + 16 + q2 * 8];
        Of = __builtin_amdgcn_mfma_f32_32x32x16_bf16(Vf0, Pf0, Of, 0, 0, 0);
        Of = __builtin_amdgcn_mfma_f32_32x32x16_bf16(Vf1, Pf1, Of, 0, 0, 0);
    }

    // --- normalize and write O^T: lane holds O[d=(r&3)+8*(r>>2)+4*q2][q] ---
    const float rl = 1.f / l_i;
#pragma unroll
    for (int r = 0; r < 16; ++r) {
        const int d = (r & 3) + 8 * (r >> 2) + 4 * q2;
        AO[base + (size_t)d * N_DIM + q] = f32_to_bf16(Of[r] * rl);
    }
}

// ---------------------------------------------------------------------------
// GroupNorm over [B, C, N]: group g = channels 8g..8g+8, 32768 elems/group.
// ---------------------------------------------------------------------------
__global__ __launch_bounds__(256) void groupnorm_kernel(
    const float* __restrict__ Yv, const float* __restrict__ gw,
    const float* __restrict__ gb, float* __restrict__ out)
{
    const int g = blockIdx.x;
    const int b = blockIdx.y;
    const size_t base = ((size_t)b * C_DIM + (size_t)g * 8) * N_DIM;
    const float4* Y4 = (const float4*)(Yv + base);
    float4* O4 = (float4*)(out + base);
    const int t = threadIdx.x;

    float sum = 0.f, sumsq = 0.f;
    for (int i = t; i < 8192; i += 256) {
        float4 v = Y4[i];
        sum   += v.x + v.y + v.z + v.w;
        sumsq += v.x * v.x + v.y * v.y + v.z * v.z + v.w * v.w;
    }
#pragma unroll
    for (int off = 1; off < 64; off <<= 1) {
        sum   += __shfl_xor(sum, off, 64);
        sumsq += __shfl_xor(sumsq, off, 64);
    }
    __shared__ float red[10];
    const int wid = t >> 6;
    if ((t & 63) == 0) { red[wid] = sum; red[4 + wid] = sumsq; }
    __syncthreads();
    if (t == 0) {
        float s = red[0] + red[1] + red[2] + red[3];
        float qq = red[4] + red[5] + red[6] + red[7];
        float mean = s * (1.f / 32768.f);
        float var  = qq * (1.f / 32768.f) - mean * mean;
        red[8] = mean;
        red[9] = rsqrtf(var + 1e-5f);
    }
    __syncthreads();
    const float mean = red[8], rstd = red[9];
    for (int i = t; i < 8192; i += 256) {
        const int c = i >> 10;
        const float wv  = gw[g * 8 + c] * rstd;
        const float bb2 = gb[g * 8 + c];
        float4 v = Y4[i];
        float4 r;
        r.x = (v.x - mean) * wv + bb2;
        r.y = (v.y - mean) * wv + bb2;
        r.z = (v.z - mean) * wv + bb2;
        r.w = (v.w - mean) * wv + bb2;
        O4[i] = r;
    }
}

// ---------------------------------------------------------------------------
extern "C" void kernel_launch(void* const* d_in, const int* in_sizes, int n_in,
                              void* d_out, int out_size, void* d_ws, size_t ws_size,
                              hipStream_t stream)
{
    const float* query = (const float*)d_in[0];
    const float* key   = (const float*)d_in[1];
    const float* q_w   = (const float*)d_in[2];
    const float* q_b   = (const float*)d_in[3];
    const float* k_w   = (const float*)d_in[4];
    const float* k_b   = (const float*)d_in[5];
    const float* v_w   = (const float*)d_in[6];
    const float* v_b   = (const float*)d_in[7];
    const float* o_w   = (const float*)d_in[8];
    const float* o_b   = (const float*)d_in[9];
    const float* gn_w  = (const float*)d_in[10];
    const float* gn_b  = (const float*)d_in[11];

    // ws layout (bytes): [0,4M) Qbf16  [4M,8M) Kbf16  [8M,12M) Vbf16
    //                    [12M,16M) AObf16  [16M,24M) y fp32
    char* wsb = (char*)d_ws;
    short* Qb16  = (short*)(wsb);
    short* Kb16  = (short*)(wsb + (4u << 20));
    short* Vb16  = (short*)(wsb + (8u << 20));
    short* AOb16 = (short*)(wsb + (12u << 20));
    float* y     = (float*)(wsb + (16u << 20));

    // softmax scale 1/sqrt(32) * log2(e), folded into Q projection
    const float qscale = 0.17677669529663687f * 1.4426950408889634f;

    dim3 gemm_grid(N_DIM / 64, C_DIM / 64, 2);
    gemm_proj<false, true><<<gemm_grid, 256, 0, stream>>>(q_w, q_b, query, nullptr, Qb16, qscale);
    gemm_proj<false, true><<<gemm_grid, 256, 0, stream>>>(k_w, k_b, key,   nullptr, Kb16, 1.0f);
    gemm_proj<false, true><<<gemm_grid, 256, 0, stream>>>(v_w, v_b, key,   nullptr, Vb16, 1.0f);

    flash_mfma<<<dim3(N_DIM / 128, 8, 2), 256, 0, stream>>>(Qb16, Kb16, Vb16, AOb16);

    gemm_proj<true, false><<<gemm_grid, 256, 0, stream>>>(o_w, o_b, AOb16, query, y, 1.0f);

    groupnorm_kernel<<<dim3(32, 2), 256, 0, stream>>>(y, gn_w, gn_b, (float*)d_out);
}

// Round 3
// 262.067 us; speedup vs baseline: 3.5009x; 1.2151x over previous
//
#include <hip/hip_runtime.h>
#include <math.h>

#define C_DIM 256
#define N_DIM 4096

using bf16x8 = __attribute__((ext_vector_type(8))) short;   // 8 bf16 = 4 VGPRs
using f32x16 = __attribute__((ext_vector_type(16))) float;  // 32x32 MFMA acc

__device__ __forceinline__ unsigned pack_bf16_pair(float a, float b) {
    unsigned ua = __float_as_uint(a) + 0x8000u;
    unsigned ub = __float_as_uint(b) + 0x8000u;
    return (ua >> 16) | (ub & 0xFFFF0000u);
}
__device__ __forceinline__ short f32_to_bf16(float a) {
    return (short)((__float_as_uint(a) + 0x8000u) >> 16);
}
__device__ __forceinline__ float bf16_to_f32(unsigned short u) {
    return __uint_as_float(((unsigned)u) << 16);
}

// ---------------------------------------------------------------------------
// GEMM: Y[b,o,n] = outscale*(sum_c W[o,c]*X[b,c,n] + bias[o]) (+res)
// OUT_MODE: 0 = fp32 natural [c][n] (+res), 1 = bf16 natural [c][n],
//           2 = bf16 per-head transposed [(b*8+h)*N + n][d]  (d = c&31)
// Typed restrict pointers throughout (unused ones passed null).
// ---------------------------------------------------------------------------
template <int IN_BF16, int OUT_MODE>
__global__ __launch_bounds__(256) void gemm_proj(
    const float* __restrict__ W, const float* __restrict__ bias,
    const float* __restrict__ Xf, const short* __restrict__ Xh,
    const float* __restrict__ res,
    float* __restrict__ Yf, short* __restrict__ Yh, float outscale)
{
    const int n0 = blockIdx.x * 64;
    const int o0 = blockIdx.y * 64;
    const int b  = blockIdx.z;
    const size_t bofs = (size_t)b * C_DIM * N_DIM;

    __shared__ float Ws[16][68];
    __shared__ float Xs[16][64];

    const int t  = threadIdx.x;
    const int tx = t & 15;
    const int ty = t >> 4;
    const int w_or = t >> 2;
    const int w_cg = t & 3;
    const int x_cr = t >> 4;
    const int x_ng = t & 15;

    float acc[4][4];
#pragma unroll
    for (int i = 0; i < 4; ++i)
#pragma unroll
        for (int j = 0; j < 4; ++j) acc[i][j] = 0.f;

    for (int c0 = 0; c0 < C_DIM; c0 += 16) {
        float4 wv = *(const float4*)&W[(size_t)(o0 + w_or) * C_DIM + c0 + 4 * w_cg];
        float4 xv;
        if (IN_BF16) {
            ushort4 u = *(const ushort4*)&Xh[bofs + (size_t)(c0 + x_cr) * N_DIM + n0 + 4 * x_ng];
            xv.x = bf16_to_f32(u.x); xv.y = bf16_to_f32(u.y);
            xv.z = bf16_to_f32(u.z); xv.w = bf16_to_f32(u.w);
        } else {
            xv = *(const float4*)&Xf[bofs + (size_t)(c0 + x_cr) * N_DIM + n0 + 4 * x_ng];
        }
        __syncthreads();
        Ws[4 * w_cg + 0][w_or] = wv.x;
        Ws[4 * w_cg + 1][w_or] = wv.y;
        Ws[4 * w_cg + 2][w_or] = wv.z;
        Ws[4 * w_cg + 3][w_or] = wv.w;
        *(float4*)&Xs[x_cr][4 * x_ng] = xv;
        __syncthreads();
#pragma unroll
        for (int kk = 0; kk < 16; ++kk) {
            float4 av = *(const float4*)&Ws[kk][4 * ty];
            float4 bv = *(const float4*)&Xs[kk][4 * tx];
            float a[4]  = {av.x, av.y, av.z, av.w};
            float bb[4] = {bv.x, bv.y, bv.z, bv.w};
#pragma unroll
            for (int i = 0; i < 4; ++i)
#pragma unroll
                for (int j = 0; j < 4; ++j)
                    acc[i][j] = fmaf(a[i], bb[j], acc[i][j]);
        }
    }

    const int ob = o0 + 4 * ty;
    float bv4[4];
#pragma unroll
    for (int i = 0; i < 4; ++i) bv4[i] = bias[ob + i];

    if (OUT_MODE == 2) {
        // transposed per-head: row n, 4 consecutive d = (ob&31)+i
        const int hh = ob >> 5;
        const int dl = ob & 31;
        short* Yt = Yh + ((size_t)(b * 8 + hh) * N_DIM) * 32;
#pragma unroll
        for (int j = 0; j < 4; ++j) {
            const int n = n0 + 4 * tx + j;
            ushort4 u;
            u.x = (unsigned short)f32_to_bf16((acc[0][j] + bv4[0]) * outscale);
            u.y = (unsigned short)f32_to_bf16((acc[1][j] + bv4[1]) * outscale);
            u.z = (unsigned short)f32_to_bf16((acc[2][j] + bv4[2]) * outscale);
            u.w = (unsigned short)f32_to_bf16((acc[3][j] + bv4[3]) * outscale);
            *(ushort4*)&Yt[(size_t)n * 32 + dl] = u;
        }
    } else {
#pragma unroll
        for (int i = 0; i < 4; ++i) {
            const int o = ob + i;
            float4 v;
            v.x = acc[i][0] + bv4[i]; v.y = acc[i][1] + bv4[i];
            v.z = acc[i][2] + bv4[i]; v.w = acc[i][3] + bv4[i];
            if (OUT_MODE == 0 && res != nullptr) {
                float4 rv = *(const float4*)&res[bofs + (size_t)o * N_DIM + n0 + 4 * tx];
                v.x += rv.x; v.y += rv.y; v.z += rv.z; v.w += rv.w;
            }
            v.x *= outscale; v.y *= outscale; v.z *= outscale; v.w *= outscale;
            if (OUT_MODE == 1) {
                ushort4 u;
                u.x = (unsigned short)f32_to_bf16(v.x);
                u.y = (unsigned short)f32_to_bf16(v.y);
                u.z = (unsigned short)f32_to_bf16(v.z);
                u.w = (unsigned short)f32_to_bf16(v.w);
                *(ushort4*)&Yh[bofs + (size_t)o * N_DIM + n0 + 4 * tx] = u;
            } else {
                *(float4*)&Yf[bofs + (size_t)o * N_DIM + n0 + 4 * tx] = v;
            }
        }
    }
}

// ---------------------------------------------------------------------------
// Flash attention, bf16 MFMA 32x32x16. NO LDS, NO barriers, static softmax.
// Qt/Kt: per-head transposed [(b*8+h)*N + n][d32] bf16 (Q pre-scaled by
// 1/sqrt(32)*log2e in its projection). Vp: natural [b][c][n] bf16.
// Block = 4 independent waves; wave owns 32 queries; 32-key tiles, K/V frags
// loaded directly from global (b128), prefetched one tile ahead.
// P^T fragments built in-register via 8x shfl_xor(32) + selects.
// ---------------------------------------------------------------------------
__global__ __launch_bounds__(256) void flash_mfma(
    const short* __restrict__ Qt, const short* __restrict__ Kt,
    const short* __restrict__ Vp, short* __restrict__ AO)
{
    const int n0 = blockIdx.x * 128;
    const int h  = blockIdx.y;
    const int b  = blockIdx.z;
    const int t    = threadIdx.x;
    const int w    = t >> 6;
    const int lane = t & 63;
    const int q2   = lane >> 5;
    const int l31  = lane & 31;
    const int q    = n0 + w * 32 + l31;

    const size_t headT = (size_t)(b * 8 + h) * N_DIM * 32;          // transposed planes
    const size_t base  = ((size_t)b * C_DIM + (size_t)h * 32) * N_DIM; // natural planes

    // Q B-frags (d-halves)
    const short* qp = Qt + headT + (size_t)q * 32;
    bf16x8 Qf0 = *(const bf16x8*)(qp + q2 * 8);
    bf16x8 Qf1 = *(const bf16x8*)(qp + 16 + q2 * 8);

    const short* kp = Kt + headT + (size_t)l31 * 32 + q2 * 8;
    const short* vp = Vp + base + (size_t)l31 * N_DIM + q2 * 8;

    bf16x8 Kc0 = *(const bf16x8*)(kp);
    bf16x8 Kc1 = *(const bf16x8*)(kp + 16);
    bf16x8 Vc0 = *(const bf16x8*)(vp);
    bf16x8 Vc1 = *(const bf16x8*)(vp + 16);
    kp += 32 * 32;   // next 32 keys (transposed rows)
    vp += 32;        // next 32 keys (natural cols)

    f32x16 Of;
#pragma unroll
    for (int r = 0; r < 16; ++r) Of[r] = 0.f;
    float ls = 0.f;

    for (int it = 0; it < N_DIM / 32; ++it) {
        // prefetch next tile (last iter reads a few KB past region, within ws; unused)
        bf16x8 Kn0 = *(const bf16x8*)(kp);
        bf16x8 Kn1 = *(const bf16x8*)(kp + 16);
        bf16x8 Vn0 = *(const bf16x8*)(vp);
        bf16x8 Vn1 = *(const bf16x8*)(vp + 16);
        kp += 32 * 32; vp += 32;

        // S^T = K . Q^T  (lane: S^T[key=(r&3)+8*(r>>2)+4*q2][q=l31], log2-domain)
        f32x16 acc;
#pragma unroll
        for (int r = 0; r < 16; ++r) acc[r] = 0.f;
        acc = __builtin_amdgcn_mfma_f32_32x32x16_bf16(Kc0, Qf0, acc, 0, 0, 0);
        acc = __builtin_amdgcn_mfma_f32_32x32x16_bf16(Kc1, Qf1, acc, 0, 0, 0);

        // static softmax: p = exp2(s), accumulate l per-lane
        float p[16];
#pragma unroll
        for (int r = 0; r < 16; ++r) { p[r] = __builtin_amdgcn_exp2f(acc[r]); ls += p[r]; }

        // pack adjacent-key pairs: u[g] = keys (8*(g>>1) + 4*q2 + 2*(g&1) + {0,1})
        unsigned u[8], xu[8];
#pragma unroll
        for (int g = 0; g < 8; ++g) u[g] = pack_bf16_pair(p[2 * g], p[2 * g + 1]);
#pragma unroll
        for (int g = 0; g < 8; ++g) xu[g] = (unsigned)__shfl_xor((int)u[g], 32, 64);

        // P^T B-frags: lane needs keys chunk + q2*8 + 0..7
        uint4 f0, f1;
        f0.x = q2 ? xu[2] : u[0];  f0.y = q2 ? xu[3] : u[1];
        f0.z = q2 ? u[2]  : xu[0]; f0.w = q2 ? u[3]  : xu[1];
        f1.x = q2 ? xu[6] : u[4];  f1.y = q2 ? xu[7] : u[5];
        f1.z = q2 ? u[6]  : xu[4]; f1.w = q2 ? u[7]  : xu[5];
        bf16x8 Pf0 = __builtin_bit_cast(bf16x8, f0);
        bf16x8 Pf1 = __builtin_bit_cast(bf16x8, f1);

        // O^T += V^T . P^T
        Of = __builtin_amdgcn_mfma_f32_32x32x16_bf16(Vc0, Pf0, Of, 0, 0, 0);
        Of = __builtin_amdgcn_mfma_f32_32x32x16_bf16(Vc1, Pf1, Of, 0, 0, 0);

        Kc0 = Kn0; Kc1 = Kn1; Vc0 = Vn0; Vc1 = Vn1;
    }

    ls += __shfl_xor(ls, 32, 64);
    const float rl = 1.f / ls;
#pragma unroll
    for (int r = 0; r < 16; ++r) {
        const int d = (r & 3) + 8 * (r >> 2) + 4 * q2;
        AO[base + (size_t)d * N_DIM + q] = f32_to_bf16(Of[r] * rl);
    }
}

// ---------------------------------------------------------------------------
// GroupNorm over [B, C, N]: group g = channels 8g..8g+8, 32768 elems/group.
// ---------------------------------------------------------------------------
__global__ __launch_bounds__(256) void groupnorm_kernel(
    const float* __restrict__ Yv, const float* __restrict__ gw,
    const float* __restrict__ gb, float* __restrict__ out)
{
    const int g = blockIdx.x;
    const int b = blockIdx.y;
    const size_t base = ((size_t)b * C_DIM + (size_t)g * 8) * N_DIM;
    const float4* Y4 = (const float4*)(Yv + base);
    float4* O4 = (float4*)(out + base);
    const int t = threadIdx.x;

    float sum = 0.f, sumsq = 0.f;
    for (int i = t; i < 8192; i += 256) {
        float4 v = Y4[i];
        sum   += v.x + v.y + v.z + v.w;
        sumsq += v.x * v.x + v.y * v.y + v.z * v.z + v.w * v.w;
    }
#pragma unroll
    for (int off = 1; off < 64; off <<= 1) {
        sum   += __shfl_xor(sum, off, 64);
        sumsq += __shfl_xor(sumsq, off, 64);
    }
    __shared__ float red[10];
    const int wid = t >> 6;
    if ((t & 63) == 0) { red[wid] = sum; red[4 + wid] = sumsq; }
    __syncthreads();
    if (t == 0) {
        float s = red[0] + red[1] + red[2] + red[3];
        float qq = red[4] + red[5] + red[6] + red[7];
        float mean = s * (1.f / 32768.f);
        float var  = qq * (1.f / 32768.f) - mean * mean;
        red[8] = mean;
        red[9] = rsqrtf(var + 1e-5f);
    }
    __syncthreads();
    const float mean = red[8], rstd = red[9];
    for (int i = t; i < 8192; i += 256) {
        const int c = i >> 10;
        const float wv  = gw[g * 8 + c] * rstd;
        const float bb2 = gb[g * 8 + c];
        float4 v = Y4[i];
        float4 r;
        r.x = (v.x - mean) * wv + bb2;
        r.y = (v.y - mean) * wv + bb2;
        r.z = (v.z - mean) * wv + bb2;
        r.w = (v.w - mean) * wv + bb2;
        O4[i] = r;
    }
}

// ---------------------------------------------------------------------------
extern "C" void kernel_launch(void* const* d_in, const int* in_sizes, int n_in,
                              void* d_out, int out_size, void* d_ws, size_t ws_size,
                              hipStream_t stream)
{
    const float* query = (const float*)d_in[0];
    const float* key   = (const float*)d_in[1];
    const float* q_w   = (const float*)d_in[2];
    const float* q_b   = (const float*)d_in[3];
    const float* k_w   = (const float*)d_in[4];
    const float* k_b   = (const float*)d_in[5];
    const float* v_w   = (const float*)d_in[6];
    const float* v_b   = (const float*)d_in[7];
    const float* o_w   = (const float*)d_in[8];
    const float* o_b   = (const float*)d_in[9];
    const float* gn_w  = (const float*)d_in[10];
    const float* gn_b  = (const float*)d_in[11];

    // ws layout (bytes): [0,4M) Qt  [4M,8M) Kt  [8M,12M) V  [12M,16M) AO  [16M,24M) y
    char* wsb = (char*)d_ws;
    short* Qt    = (short*)(wsb);
    short* Kt    = (short*)(wsb + (4u << 20));
    short* Vb16  = (short*)(wsb + (8u << 20));
    short* AOb16 = (short*)(wsb + (12u << 20));
    float* y     = (float*)(wsb + (16u << 20));

    // softmax scale 1/sqrt(32) * log2(e), folded into Q projection
    const float qscale = 0.17677669529663687f * 1.4426950408889634f;

    dim3 gemm_grid(N_DIM / 64, C_DIM / 64, 2);
    gemm_proj<0, 2><<<gemm_grid, 256, 0, stream>>>(q_w, q_b, query, nullptr, nullptr,
                                                   nullptr, Qt, qscale);
    gemm_proj<0, 2><<<gemm_grid, 256, 0, stream>>>(k_w, k_b, key, nullptr, nullptr,
                                                   nullptr, Kt, 1.0f);
    gemm_proj<0, 1><<<gemm_grid, 256, 0, stream>>>(v_w, v_b, key, nullptr, nullptr,
                                                   nullptr, Vb16, 1.0f);

    flash_mfma<<<dim3(N_DIM / 128, 8, 2), 256, 0, stream>>>(Qt, Kt, Vb16, AOb16);

    gemm_proj<1, 0><<<gemm_grid, 256, 0, stream>>>(o_w, o_b, nullptr, AOb16, query,
                                                   y, nullptr, 1.0f);

    groupnorm_kernel<<<dim3(32, 2), 256, 0, stream>>>(y, gn_w, gn_b, (float*)d_out);
}

// Round 4
// 257.844 us; speedup vs baseline: 3.5582x; 1.0164x over previous
//
#include <hip/hip_runtime.h>
#include <math.h>

#define C_DIM 256
#define N_DIM 4096
#define NHEAD 8

using bf16x8 = __attribute__((ext_vector_type(8))) short;   // 8 bf16 = 4 VGPRs
using f32x16 = __attribute__((ext_vector_type(16))) float;  // 32x32 MFMA acc

__device__ __forceinline__ short f32_to_bf16(float a) {
    return (short)((__float_as_uint(a) + 0x8000u) >> 16);
}
__device__ __forceinline__ float bf16_to_f32(unsigned short u) {
    return __uint_as_float(((unsigned)u) << 16);
}
// lo16 = hi16(a), hi16 = hi16(b): single v_perm_b32 (truncation rounding)
__device__ __forceinline__ unsigned pack_trunc(float a, float b) {
    return __builtin_amdgcn_perm(__float_as_uint(b), __float_as_uint(a), 0x07060302u);
}

// ---------------------------------------------------------------------------
// Convert q_w/k_w/v_w fp32 -> bf16, concatenated [3][256*256].
// ---------------------------------------------------------------------------
__global__ __launch_bounds__(256) void conv_w3(
    const float* __restrict__ qw, const float* __restrict__ kw,
    const float* __restrict__ vw, short* __restrict__ dst)
{
    const int idx = (blockIdx.x * 256 + threadIdx.x) * 4;
    const int which = blockIdx.y;
    const float* src = which == 0 ? qw : (which == 1 ? kw : vw);
    float4 v = *(const float4*)&src[idx];
    ushort4 u;
    u.x = (unsigned short)f32_to_bf16(v.x);
    u.y = (unsigned short)f32_to_bf16(v.y);
    u.z = (unsigned short)f32_to_bf16(v.z);
    u.w = (unsigned short)f32_to_bf16(v.w);
    *(ushort4*)&dst[which * 65536 + idx] = u;
}

// ---------------------------------------------------------------------------
// Transpose [b][256 c][4096 n] (fp32 or bf16) -> [b][4096 n][256 c] bf16.
// 64x64 LDS tile.
// ---------------------------------------------------------------------------
template <int IN_BF16>
__global__ __launch_bounds__(256) void transpose_cn(
    const float* __restrict__ Xf, const short* __restrict__ Xh,
    short* __restrict__ Out)
{
    const int n0 = blockIdx.x * 64;
    const int c0 = blockIdx.y * 64;
    const int b  = blockIdx.z;
    __shared__ short Ts[64][68];
    const int t = threadIdx.x;
    const int cl  = t >> 4;
    const int nl4 = (t & 15) * 4;
    const size_t ibase = (size_t)b * C_DIM * N_DIM;
#pragma unroll
    for (int p = 0; p < 4; ++p) {
        const int c = cl + p * 16;
        short s4[4];
        if (IN_BF16) {
            ushort4 u = *(const ushort4*)&Xh[ibase + (size_t)(c0 + c) * N_DIM + n0 + nl4];
            s4[0] = (short)u.x; s4[1] = (short)u.y; s4[2] = (short)u.z; s4[3] = (short)u.w;
        } else {
            float4 v = *(const float4*)&Xf[ibase + (size_t)(c0 + c) * N_DIM + n0 + nl4];
            s4[0] = f32_to_bf16(v.x); s4[1] = f32_to_bf16(v.y);
            s4[2] = f32_to_bf16(v.z); s4[3] = f32_to_bf16(v.w);
        }
#pragma unroll
        for (int j = 0; j < 4; ++j) Ts[nl4 + j][c] = s4[j];
    }
    __syncthreads();
    const size_t obase = (size_t)b * N_DIM * C_DIM;
    const int cq = (t & 15) * 4;
    const int nr = t >> 4;
#pragma unroll
    for (int p = 0; p < 4; ++p) {
        const int n = nr + p * 16;
        ushort4 u = *(const ushort4*)&Ts[n][cq];
        *(ushort4*)&Out[obase + (size_t)(n0 + n) * C_DIM + c0 + cq] = u;
    }
}

// ---------------------------------------------------------------------------
// No-LDS MFMA GEMM over K=256 (fully unrolled, 16 MFMAs/wave).
// Wave = 32o x 32n C-tile; block = 4 waves (64o x 64n); grid (64 nT, 4 oT, 2 b).
// A-frag: lane holds A[m=lane&31][k=(lane>>5)*8+j]; B-frag: B-source [n][k].
// MODE 0: fp32 out [c][n] + res; A = Wf (fp32, cvt in-flight), B = Xt
// MODE 1: bf16 out [c][n];       A = Wb,                       B = Xt
// MODE 2: bf16 out per-head [n][32]: D = X*W^T -> A = Xt, B = Wb
// ---------------------------------------------------------------------------
template <int MODE>
__global__ __launch_bounds__(256) void gemm_mfma(
    const short* __restrict__ Wb, const float* __restrict__ Wf,
    const float* __restrict__ bias, const short* __restrict__ Xt,
    const float* __restrict__ res, short* __restrict__ Yh,
    float* __restrict__ Yf, float outscale)
{
    const int t = threadIdx.x, w = t >> 6, lane = t & 63;
    const int q2 = lane >> 5, l31 = lane & 31;
    const int n0 = blockIdx.x * 64 + (w >> 1) * 32;
    const int o0 = blockIdx.y * 64 + (w & 1) * 32;
    const int b  = blockIdx.z;
    const short* xrow = Xt + (size_t)b * N_DIM * C_DIM + (size_t)(n0 + l31) * C_DIM + q2 * 8;

    f32x16 acc;
#pragma unroll
    for (int r = 0; r < 16; ++r) acc[r] = 0.f;

    if (MODE == 0) {
        const float* wrow = Wf + (size_t)(o0 + l31) * C_DIM + q2 * 8;
#pragma unroll
        for (int kc = 0; kc < C_DIM; kc += 16) {
            float4 a0 = *(const float4*)&wrow[kc];
            float4 a1 = *(const float4*)&wrow[kc + 4];
            bf16x8 af;
            af[0] = f32_to_bf16(a0.x); af[1] = f32_to_bf16(a0.y);
            af[2] = f32_to_bf16(a0.z); af[3] = f32_to_bf16(a0.w);
            af[4] = f32_to_bf16(a1.x); af[5] = f32_to_bf16(a1.y);
            af[6] = f32_to_bf16(a1.z); af[7] = f32_to_bf16(a1.w);
            bf16x8 bf = *(const bf16x8*)&xrow[kc];
            acc = __builtin_amdgcn_mfma_f32_32x32x16_bf16(af, bf, acc, 0, 0, 0);
        }
    } else {
        const short* wrow = Wb + (size_t)(o0 + l31) * C_DIM + q2 * 8;
#pragma unroll
        for (int kc = 0; kc < C_DIM; kc += 16) {
            bf16x8 af = *(const bf16x8*)&wrow[kc];
            bf16x8 bf = *(const bf16x8*)&xrow[kc];
            if (MODE == 2)
                acc = __builtin_amdgcn_mfma_f32_32x32x16_bf16(bf, af, acc, 0, 0, 0);
            else
                acc = __builtin_amdgcn_mfma_f32_32x32x16_bf16(af, bf, acc, 0, 0, 0);
        }
    }

    if (MODE == 2) {
        const int head = o0 >> 5;   // o0 is a multiple of 32
        const float bi = bias[o0 + l31];
        short* Yt = Yh + (size_t)(b * NHEAD + head) * N_DIM * 32;
#pragma unroll
        for (int r = 0; r < 16; ++r) {
            const int n = n0 + (r & 3) + 8 * (r >> 2) + 4 * q2;
            Yt[(size_t)n * 32 + l31] = f32_to_bf16((acc[r] + bi) * outscale);
        }
    } else {
#pragma unroll
        for (int r = 0; r < 16; ++r) {
            const int o = o0 + (r & 3) + 8 * (r >> 2) + 4 * q2;
            const int n = n0 + l31;
            const size_t addr = (size_t)b * C_DIM * N_DIM + (size_t)o * N_DIM + n;
            float v = acc[r] + bias[o];
            if (MODE == 0) {
                v += res[addr];
                Yf[addr] = v;
            } else {
                Yh[addr] = f32_to_bf16(v);
            }
        }
    }
}

// ---------------------------------------------------------------------------
// Flash attention, bf16 MFMA 32x32x16, no LDS/barriers, static softmax,
// split-K over SPLIT chunks (partials unnormalized bf16 + l per chunk).
// ---------------------------------------------------------------------------
template <int SPLIT>
__global__ __launch_bounds__(256) void flash_mfma(
    const short* __restrict__ Qt, const short* __restrict__ Kt,
    const short* __restrict__ Vp, short* __restrict__ AO,
    short* __restrict__ Opart, float* __restrict__ lpart)
{
    const int n0 = blockIdx.x * 128;
    const int h  = blockIdx.y;
    const int z  = blockIdx.z;
    const int b  = z / SPLIT;
    const int s  = z % SPLIT;
    const int CHUNK = N_DIM / SPLIT;
    const int t = threadIdx.x, w = t >> 6, lane = t & 63;
    const int q2 = lane >> 5, l31 = lane & 31;
    const int q  = n0 + w * 32 + l31;
    const int bhp = b * NHEAD + h;

    const size_t headT = (size_t)bhp * N_DIM * 32;
    const size_t base  = ((size_t)b * C_DIM + (size_t)h * 32) * N_DIM;

    const short* qp = Qt + headT + (size_t)q * 32;
    bf16x8 Qf0 = *(const bf16x8*)(qp + q2 * 8);
    bf16x8 Qf1 = *(const bf16x8*)(qp + 16 + q2 * 8);

    const int k0 = s * CHUNK;
    const short* kp = Kt + headT + (size_t)(k0 + l31) * 32 + q2 * 8;
    const short* vp = Vp + base + (size_t)l31 * N_DIM + k0 + q2 * 8;

    bf16x8 Kc0 = *(const bf16x8*)(kp);
    bf16x8 Kc1 = *(const bf16x8*)(kp + 16);
    bf16x8 Vc0 = *(const bf16x8*)(vp);
    bf16x8 Vc1 = *(const bf16x8*)(vp + 16);
    kp += 32 * 32; vp += 32;

    f32x16 Of;
#pragma unroll
    for (int r = 0; r < 16; ++r) Of[r] = 0.f;
    float ls = 0.f;

    for (int it = 0; it < CHUNK / 32; ++it) {
        bf16x8 Kn0 = *(const bf16x8*)(kp);
        bf16x8 Kn1 = *(const bf16x8*)(kp + 16);
        bf16x8 Vn0 = *(const bf16x8*)(vp);
        bf16x8 Vn1 = *(const bf16x8*)(vp + 16);
        kp += 32 * 32; vp += 32;

        f32x16 acc;
#pragma unroll
        for (int r = 0; r < 16; ++r) acc[r] = 0.f;
        acc = __builtin_amdgcn_mfma_f32_32x32x16_bf16(Kc0, Qf0, acc, 0, 0, 0);
        acc = __builtin_amdgcn_mfma_f32_32x32x16_bf16(Kc1, Qf1, acc, 0, 0, 0);

        float p[16];
#pragma unroll
        for (int r = 0; r < 16; ++r) { p[r] = __builtin_amdgcn_exp2f(acc[r]); ls += p[r]; }

        unsigned u[8], xu[8];
#pragma unroll
        for (int g = 0; g < 8; ++g) u[g] = pack_trunc(p[2 * g], p[2 * g + 1]);
#pragma unroll
        for (int g = 0; g < 8; ++g) xu[g] = (unsigned)__shfl_xor((int)u[g], 32, 64);

        uint4 f0, f1;
        f0.x = q2 ? xu[2] : u[0];  f0.y = q2 ? xu[3] : u[1];
        f0.z = q2 ? u[2]  : xu[0]; f0.w = q2 ? u[3]  : xu[1];
        f1.x = q2 ? xu[6] : u[4];  f1.y = q2 ? xu[7] : u[5];
        f1.z = q2 ? u[6]  : xu[4]; f1.w = q2 ? u[7]  : xu[5];
        bf16x8 Pf0 = __builtin_bit_cast(bf16x8, f0);
        bf16x8 Pf1 = __builtin_bit_cast(bf16x8, f1);

        Of = __builtin_amdgcn_mfma_f32_32x32x16_bf16(Vc0, Pf0, Of, 0, 0, 0);
        Of = __builtin_amdgcn_mfma_f32_32x32x16_bf16(Vc1, Pf1, Of, 0, 0, 0);

        Kc0 = Kn0; Kc1 = Kn1; Vc0 = Vn0; Vc1 = Vn1;
    }

    ls += __shfl_xor(ls, 32, 64);
    if (SPLIT == 1) {
        const float rl = 1.f / ls;
#pragma unroll
        for (int r = 0; r < 16; ++r) {
            const int d = (r & 3) + 8 * (r >> 2) + 4 * q2;
            AO[base + (size_t)d * N_DIM + q] = f32_to_bf16(Of[r] * rl);
        }
    } else {
#pragma unroll
        for (int r = 0; r < 16; ++r) {
            const int d = (r & 3) + 8 * (r >> 2) + 4 * q2;
            Opart[((size_t)(s * 16 + bhp) * 32 + d) * N_DIM + q] = f32_to_bf16(Of[r]);
        }
        lpart[(size_t)(s * 16 + bhp) * N_DIM + q] = ls;
    }
}

// ---------------------------------------------------------------------------
// Combine 4 split-K partials -> normalized AOt [b][n][256] bf16 (transposed).
// Block: (64 n) x (32 d) tile for one (b,h). Grid (64, 16).
// ---------------------------------------------------------------------------
__global__ __launch_bounds__(256) void combine4(
    const short* __restrict__ Opart, const float* __restrict__ lpart,
    short* __restrict__ AOt)
{
    const int n0 = blockIdx.x * 64;
    const int p  = blockIdx.y;          // b*8+h
    const int bb = p >> 3, hh = p & 7;
    const int t = threadIdx.x;
    __shared__ float linv[64];
    __shared__ short Ts[64][36];

    if (t < 64) {
        float sum = 0.f;
#pragma unroll
        for (int s = 0; s < 4; ++s)
            sum += lpart[(size_t)(s * 16 + p) * N_DIM + n0 + t];
        linv[t] = 1.f / sum;
    }

    const int d  = t >> 3;
    const int n8 = (t & 7) * 8;
    float a[8];
#pragma unroll
    for (int j = 0; j < 8; ++j) a[j] = 0.f;
#pragma unroll
    for (int s = 0; s < 4; ++s) {
        const size_t rb = ((size_t)(s * 16 + p) * 32 + d) * N_DIM + n0 + n8;
        ushort4 u0 = *(const ushort4*)&Opart[rb];
        ushort4 u1 = *(const ushort4*)&Opart[rb + 4];
        a[0] += bf16_to_f32(u0.x); a[1] += bf16_to_f32(u0.y);
        a[2] += bf16_to_f32(u0.z); a[3] += bf16_to_f32(u0.w);
        a[4] += bf16_to_f32(u1.x); a[5] += bf16_to_f32(u1.y);
        a[6] += bf16_to_f32(u1.z); a[7] += bf16_to_f32(u1.w);
    }
    __syncthreads();   // linv ready
#pragma unroll
    for (int j = 0; j < 8; ++j)
        Ts[n8 + j][d] = f32_to_bf16(a[j] * linv[n8 + j]);
    __syncthreads();
    const int dq = (t & 7) * 4;
    const int nr = t >> 3;              // 0..31
#pragma unroll
    for (int p2 = 0; p2 < 2; ++p2) {
        const int n = nr + p2 * 32;
        ushort4 u = *(const ushort4*)&Ts[n][dq];
        *(ushort4*)&AOt[(size_t)bb * N_DIM * C_DIM + (size_t)(n0 + n) * C_DIM + hh * 32 + dq] = u;
    }
}

// ---------------------------------------------------------------------------
// In-place GroupNorm over [B, C, N]: group g = channels 8g..8g+8.
// ---------------------------------------------------------------------------
__global__ __launch_bounds__(256) void groupnorm_kernel(
    float* __restrict__ data, const float* __restrict__ gw,
    const float* __restrict__ gb)
{
    const int g = blockIdx.x;
    const int b = blockIdx.y;
    const size_t base = ((size_t)b * C_DIM + (size_t)g * 8) * N_DIM;
    float4* Y4 = (float4*)(data + base);
    const int t = threadIdx.x;

    float sum = 0.f, sumsq = 0.f;
    for (int i = t; i < 8192; i += 256) {
        float4 v = Y4[i];
        sum   += v.x + v.y + v.z + v.w;
        sumsq += v.x * v.x + v.y * v.y + v.z * v.z + v.w * v.w;
    }
#pragma unroll
    for (int off = 1; off < 64; off <<= 1) {
        sum   += __shfl_xor(sum, off, 64);
        sumsq += __shfl_xor(sumsq, off, 64);
    }
    __shared__ float red[10];
    const int wid = t >> 6;
    if ((t & 63) == 0) { red[wid] = sum; red[4 + wid] = sumsq; }
    __syncthreads();
    if (t == 0) {
        float s = red[0] + red[1] + red[2] + red[3];
        float qq = red[4] + red[5] + red[6] + red[7];
        float mean = s * (1.f / 32768.f);
        float var  = qq * (1.f / 32768.f) - mean * mean;
        red[8] = mean;
        red[9] = rsqrtf(var + 1e-5f);
    }
    __syncthreads();
    const float mean = red[8], rstd = red[9];
    for (int i = t; i < 8192; i += 256) {
        const int c = i >> 10;
        const float wv  = gw[g * 8 + c] * rstd;
        const float bb2 = gb[g * 8 + c];
        float4 v = Y4[i];
        float4 r;
        r.x = (v.x - mean) * wv + bb2;
        r.y = (v.y - mean) * wv + bb2;
        r.z = (v.z - mean) * wv + bb2;
        r.w = (v.w - mean) * wv + bb2;
        Y4[i] = r;
    }
}

// ---------------------------------------------------------------------------
extern "C" void kernel_launch(void* const* d_in, const int* in_sizes, int n_in,
                              void* d_out, int out_size, void* d_ws, size_t ws_size,
                              hipStream_t stream)
{
    const float* query = (const float*)d_in[0];
    const float* key   = (const float*)d_in[1];
    const float* q_w   = (const float*)d_in[2];
    const float* q_b   = (const float*)d_in[3];
    const float* k_w   = (const float*)d_in[4];
    const float* k_b   = (const float*)d_in[5];
    const float* v_w   = (const float*)d_in[6];
    const float* v_b   = (const float*)d_in[7];
    const float* o_w   = (const float*)d_in[8];
    const float* o_b   = (const float*)d_in[9];
    const float* gn_w  = (const float*)d_in[10];
    const float* gn_b  = (const float*)d_in[11];

    // ws layout (MiB): [0,4) Qt  [4,8) Kt  [8,12) V  [12,16) AOt (Wb aliased at
    // its head, dead before AOt written)  [16,20) Qx (fallback AO aliases)
    // [20,24) Kx  [24,40) Opart  [40,41) lpart.  y lives in d_out (in-place GN).
    char* wsb = (char*)d_ws;
    short* Qt    = (short*)(wsb);
    short* Kt    = (short*)(wsb + (4u  << 20));
    short* Vn    = (short*)(wsb + (8u  << 20));
    short* AOt   = (short*)(wsb + (12u << 20));
    short* Wb    = (short*)(wsb + (12u << 20));   // 3*128KB, dead before AOt written
    short* Qx    = (short*)(wsb + (16u << 20));
    short* Kx    = (short*)(wsb + (20u << 20));
    short* AOfb  = Qx;                            // fallback AO (Qx dead by then)
    short* Opart = (short*)(wsb + (24u << 20));
    float* lpart = (float*)(wsb + (40u << 20));
    float* y     = (float*)d_out;

    const bool use_split = ws_size >= ((size_t)41 << 20);
    // softmax scale 1/sqrt(32) * log2(e), folded into Q projection
    const float qscale = 0.17677669529663687f * 1.4426950408889634f;

    conv_w3<<<dim3(64, 3), 256, 0, stream>>>(q_w, k_w, v_w, Wb);
    transpose_cn<0><<<dim3(64, 4, 2), 256, 0, stream>>>(query, nullptr, Qx);
    transpose_cn<0><<<dim3(64, 4, 2), 256, 0, stream>>>(key,   nullptr, Kx);

    dim3 gg(64, 4, 2);
    gemm_mfma<2><<<gg, 256, 0, stream>>>(Wb,          nullptr, q_b, Qx, nullptr, Qt, nullptr, qscale);
    gemm_mfma<2><<<gg, 256, 0, stream>>>(Wb + 65536,  nullptr, k_b, Kx, nullptr, Kt, nullptr, 1.0f);
    gemm_mfma<1><<<gg, 256, 0, stream>>>(Wb + 131072, nullptr, v_b, Kx, nullptr, Vn, nullptr, 1.0f);

    if (use_split) {
        flash_mfma<4><<<dim3(32, 8, 8), 256, 0, stream>>>(Qt, Kt, Vn, nullptr, Opart, lpart);
        combine4<<<dim3(64, 16), 256, 0, stream>>>(Opart, lpart, AOt);
    } else {
        flash_mfma<1><<<dim3(32, 8, 2), 256, 0, stream>>>(Qt, Kt, Vn, AOfb, nullptr, nullptr);
        transpose_cn<1><<<dim3(64, 4, 2), 256, 0, stream>>>(nullptr, AOfb, AOt);
    }

    gemm_mfma<0><<<gg, 256, 0, stream>>>(nullptr, o_w, o_b, AOt, query, nullptr, y, 1.0f);
    groupnorm_kernel<<<dim3(32, 2), 256, 0, stream>>>(y, gn_w, gn_b);
}

// Round 5
// 186.609 us; speedup vs baseline: 4.9166x; 1.3817x over previous
//
#include <hip/hip_runtime.h>
#include <math.h>

#define C_DIM 256
#define N_DIM 4096
#define NHEAD 8

using bf16x8 = __attribute__((ext_vector_type(8))) short;   // 8 bf16 = 4 VGPRs
using f32x16 = __attribute__((ext_vector_type(16))) float;  // 32x32 MFMA acc

__device__ __forceinline__ short f32_to_bf16(float a) {
    return (short)((__float_as_uint(a) + 0x8000u) >> 16);
}
__device__ __forceinline__ float bf16_to_f32(unsigned short u) {
    return __uint_as_float(((unsigned)u) << 16);
}
// lo16 = hi16(a), hi16 = hi16(b): single v_perm_b32 (truncation rounding)
__device__ __forceinline__ unsigned pack_trunc(float a, float b) {
    return __builtin_amdgcn_perm(__float_as_uint(b), __float_as_uint(a), 0x07060302u);
}

// ---------------------------------------------------------------------------
// Fragment-order ("swizzled") layouts, index in shorts.
// Big planes (rows x 256 cols): per 32-row tile: [16 kc][2 q2][32 row][8 c]
__device__ __forceinline__ int SWZ(int m, int c) {
    return (m >> 5) * 8192 + (c >> 4) * 512 + ((c >> 3) & 1) * 256 + (m & 31) * 8 + (c & 7);
}
// Q/K head planes (N x 32d): per 32-i tile: [2 dh][2 q2][32 i][8 d]
__device__ __forceinline__ int HS(int i, int d) {
    return (i >> 5) * 1024 + (d >> 4) * 512 + ((d >> 3) & 1) * 256 + (i & 31) * 8 + (d & 7);
}
// V head planes (32d x N): per 32-k tile: [2 kh][2 q2][32 d][8 k]
__device__ __forceinline__ int VS(int d, int k) {
    return (k >> 5) * 1024 + ((k >> 4) & 1) * 512 + ((k >> 3) & 1) * 256 + d * 8 + (k & 7);
}

// ---------------------------------------------------------------------------
// prep: z<4 -> transpose query/key [c][n] fp32 -> swizzled bf16 [n][c] planes
//       z==4 -> convert 4 weight planes fp32 -> swizzled bf16
// ---------------------------------------------------------------------------
__global__ __launch_bounds__(256) void prep(
    const float* __restrict__ query, const float* __restrict__ key,
    const float* __restrict__ qw, const float* __restrict__ kw,
    const float* __restrict__ vw, const float* __restrict__ ow,
    short* __restrict__ Qx, short* __restrict__ Kx, short* __restrict__ Wsw)
{
    const int t = threadIdx.x;
    if (blockIdx.z == 4) {
        const int p = blockIdx.y;
        const float* src = (p == 0) ? qw : (p == 1) ? kw : (p == 2) ? vw : ow;
        const int idx = (blockIdx.x * 256 + t) * 4;
        const int o = idx >> 8, c = idx & 255;
        float4 v = *(const float4*)&src[idx];
        short* dst = Wsw + p * 65536 + SWZ(o, c);
        dst[0] = f32_to_bf16(v.x); dst[1] = f32_to_bf16(v.y);
        dst[2] = f32_to_bf16(v.z); dst[3] = f32_to_bf16(v.w);
        return;
    }
    __shared__ short Ts[64][72];   // [n-local][c-local], stride 144 B (16B-mult)
    const int z = blockIdx.z;
    const float* in = (z < 2) ? query : key;
    short* out = ((z < 2) ? Qx : Kx) + (size_t)(z & 1) * N_DIM * C_DIM;
    const size_t ibase = (size_t)(z & 1) * C_DIM * N_DIM;
    const int n0 = blockIdx.x * 64, c0 = blockIdx.y * 64;
    const int cl = t >> 4, nl4 = (t & 15) * 4;
#pragma unroll
    for (int p = 0; p < 4; ++p) {
        const int c = cl + p * 16;
        float4 v = *(const float4*)&in[ibase + (size_t)(c0 + c) * N_DIM + n0 + nl4];
        Ts[nl4 + 0][c] = f32_to_bf16(v.x);
        Ts[nl4 + 1][c] = f32_to_bf16(v.y);
        Ts[nl4 + 2][c] = f32_to_bf16(v.z);
        Ts[nl4 + 3][c] = f32_to_bf16(v.w);
    }
    __syncthreads();
    const int nl = t >> 3, cg = t & 7;
#pragma unroll
    for (int half = 0; half < 2; ++half) {
        const int nloc = nl + half * 32;
        const int c = c0 + cg * 8;
        uint4 val = *(const uint4*)&Ts[nloc][cg * 8];
        *(uint4*)&out[SWZ(n0 + nloc, c)] = val;   // c&7==0 -> 16B aligned
    }
}

// ---------------------------------------------------------------------------
// QKV projection: one kernel, z = proj*2 + batch. Block = 4 waves, 64n x 64o.
// All A/B fragment loads fully coalesced from swizzled planes.
// proj 0/1 (Q/K): D = X.W^T (m=query), epilogue -> swizzled head plane HS.
// proj 2   (V):   D = W.X   (m=channel), epilogue -> swizzled head plane VS.
// ---------------------------------------------------------------------------
__global__ __launch_bounds__(256) void qkv_gemm(
    const short* __restrict__ Wsw, const short* __restrict__ Qx,
    const short* __restrict__ Kx,
    const float* __restrict__ q_b, const float* __restrict__ k_b,
    const float* __restrict__ v_b,
    short* __restrict__ Qt, short* __restrict__ Kt, short* __restrict__ Vt,
    float qscale)
{
    const int t = threadIdx.x, w = t >> 6, lane = t & 63;
    const int q2 = lane >> 5, l31 = lane & 31;
    const int proj = blockIdx.z >> 1, b = blockIdx.z & 1;
    const int n0 = blockIdx.x * 64 + (w >> 1) * 32;
    const int o0 = blockIdx.y * 64 + (w & 1) * 32;
    const short* X = ((proj == 0) ? Qx : Kx) + (size_t)b * N_DIM * C_DIM;
    const short* W = Wsw + proj * 65536;
    const float* bias = (proj == 0) ? q_b : (proj == 1) ? k_b : v_b;
    const int xbase = (n0 >> 5) * 8192 + q2 * 256 + l31 * 8;
    const int wbase = (o0 >> 5) * 8192 + q2 * 256 + l31 * 8;

    f32x16 acc;
#pragma unroll
    for (int r = 0; r < 16; ++r) acc[r] = 0.f;

#pragma unroll 4
    for (int kc = 0; kc < C_DIM; kc += 16) {
        bf16x8 xf = *(const bf16x8*)&X[xbase + (kc >> 4) * 512];
        bf16x8 wf = *(const bf16x8*)&W[wbase + (kc >> 4) * 512];
        if (proj == 2)
            acc = __builtin_amdgcn_mfma_f32_32x32x16_bf16(wf, xf, acc, 0, 0, 0);
        else
            acc = __builtin_amdgcn_mfma_f32_32x32x16_bf16(xf, wf, acc, 0, 0, 0);
    }

    const int head = o0 >> 5;
    if (proj < 2) {
        short* OH = ((proj == 0) ? Qt : Kt) + (size_t)(b * NHEAD + head) * N_DIM * 32;
        const float bi = bias[o0 + l31];
        const float sc = (proj == 0) ? qscale : 1.f;
        const int cbase = (n0 >> 5) * 1024 + (l31 >> 4) * 512 + ((l31 >> 3) & 1) * 256 + (l31 & 7);
#pragma unroll
        for (int r = 0; r < 16; ++r) {
            const int qs = (r & 3) + 8 * (r >> 2) + 4 * q2;   // local query 0..31
            OH[cbase + qs * 8] = f32_to_bf16((acc[r] + bi) * sc);
        }
    } else {
        short* VH = Vt + (size_t)(b * NHEAD + head) * N_DIM * 32;
        // k = n0 + l31; n0 multiple of 32
        const int kbase = (n0 >> 5) * 1024 + (l31 >> 4) * 512 + ((l31 >> 3) & 1) * 256 + (l31 & 7);
#pragma unroll
        for (int r = 0; r < 16; ++r) {
            const int ds = (r & 3) + 8 * (r >> 2) + 4 * q2;   // local channel 0..31
            VH[kbase + ds * 8] = f32_to_bf16(acc[r] + bias[o0 + ds]);
        }
    }
}

// ---------------------------------------------------------------------------
// Flash attention (identical math to verified r4 kernel), swizzled operand
// planes: every frag load is one fully-coalesced 1KB b128 wave access.
// SPLIT=4 over keys; blockIdx.z = b*4 + s.
// ---------------------------------------------------------------------------
__global__ __launch_bounds__(256) void flash_mfma(
    const short* __restrict__ Qt, const short* __restrict__ Kt,
    const short* __restrict__ Vt, short* __restrict__ Opart,
    float* __restrict__ lpart)
{
    const int n0 = blockIdx.x * 128;
    const int h  = blockIdx.y;
    const int z  = blockIdx.z;
    const int b  = z >> 2, s = z & 3;
    const int CHUNK = N_DIM / 4;
    const int t = threadIdx.x, w = t >> 6, lane = t & 63;
    const int q2 = lane >> 5, l31 = lane & 31;
    const int q  = n0 + w * 32 + l31;
    const int bhp = b * NHEAD + h;
    const size_t hb = (size_t)bhp * N_DIM * 32;
    const size_t base = ((size_t)b * C_DIM + (size_t)h * 32) * N_DIM;  // Opart natural

    const int qoff = (q >> 5) * 1024 + q2 * 256 + (q & 31) * 8;
    bf16x8 Qf0 = *(const bf16x8*)&Qt[hb + qoff];
    bf16x8 Qf1 = *(const bf16x8*)&Qt[hb + qoff + 512];

    int off = ((s * CHUNK) >> 5) * 1024 + q2 * 256 + l31 * 8;
    bf16x8 Kc0 = *(const bf16x8*)&Kt[hb + off];
    bf16x8 Kc1 = *(const bf16x8*)&Kt[hb + off + 512];
    bf16x8 Vc0 = *(const bf16x8*)&Vt[hb + off];
    bf16x8 Vc1 = *(const bf16x8*)&Vt[hb + off + 512];
    off += 1024;

    f32x16 Of;
#pragma unroll
    for (int r = 0; r < 16; ++r) Of[r] = 0.f;
    float ls = 0.f;

    for (int it = 0; it < CHUNK / 32; ++it) {
        // prefetch next 32-key tile (last iter overruns into adjacent ws; unused)
        bf16x8 Kn0 = *(const bf16x8*)&Kt[hb + off];
        bf16x8 Kn1 = *(const bf16x8*)&Kt[hb + off + 512];
        bf16x8 Vn0 = *(const bf16x8*)&Vt[hb + off];
        bf16x8 Vn1 = *(const bf16x8*)&Vt[hb + off + 512];
        off += 1024;

        // S^T = K . Q^T  (lane: S^T[key=(r&3)+8*(r>>2)+4*q2][q=l31], log2-domain)
        f32x16 acc;
#pragma unroll
        for (int r = 0; r < 16; ++r) acc[r] = 0.f;
        acc = __builtin_amdgcn_mfma_f32_32x32x16_bf16(Kc0, Qf0, acc, 0, 0, 0);
        acc = __builtin_amdgcn_mfma_f32_32x32x16_bf16(Kc1, Qf1, acc, 0, 0, 0);

        float p[16];
#pragma unroll
        for (int r = 0; r < 16; ++r) { p[r] = __builtin_amdgcn_exp2f(acc[r]); ls += p[r]; }

        unsigned u[8], xu[8];
#pragma unroll
        for (int g = 0; g < 8; ++g) u[g] = pack_trunc(p[2 * g], p[2 * g + 1]);
#pragma unroll
        for (int g = 0; g < 8; ++g) xu[g] = (unsigned)__shfl_xor((int)u[g], 32, 64);

        uint4 f0, f1;
        f0.x = q2 ? xu[2] : u[0];  f0.y = q2 ? xu[3] : u[1];
        f0.z = q2 ? u[2]  : xu[0]; f0.w = q2 ? u[3]  : xu[1];
        f1.x = q2 ? xu[6] : u[4];  f1.y = q2 ? xu[7] : u[5];
        f1.z = q2 ? u[6]  : xu[4]; f1.w = q2 ? u[7]  : xu[5];
        bf16x8 Pf0 = __builtin_bit_cast(bf16x8, f0);
        bf16x8 Pf1 = __builtin_bit_cast(bf16x8, f1);

        Of = __builtin_amdgcn_mfma_f32_32x32x16_bf16(Vc0, Pf0, Of, 0, 0, 0);
        Of = __builtin_amdgcn_mfma_f32_32x32x16_bf16(Vc1, Pf1, Of, 0, 0, 0);

        Kc0 = Kn0; Kc1 = Kn1; Vc0 = Vn0; Vc1 = Vn1;
    }

    ls += __shfl_xor(ls, 32, 64);
#pragma unroll
    for (int r = 0; r < 16; ++r) {
        const int d = (r & 3) + 8 * (r >> 2) + 4 * q2;
        Opart[((size_t)(s * 16 + bhp) * 32 + d) * N_DIM + q] = f32_to_bf16(Of[r]);
    }
    lpart[(size_t)(s * 16 + bhp) * N_DIM + q] = ls;
}

// ---------------------------------------------------------------------------
// Combine 4 split-K partials -> normalized AOt, swizzled [n][c] bf16.
// ---------------------------------------------------------------------------
__global__ __launch_bounds__(256) void combine4(
    const short* __restrict__ Opart, const float* __restrict__ lpart,
    short* __restrict__ AOt)
{
    const int n0 = blockIdx.x * 64;
    const int p  = blockIdx.y;          // b*8+h
    const int bb = p >> 3, hh = p & 7;
    const int t = threadIdx.x;
    __shared__ float linv[64];
    __shared__ short Ts[64][36];

    if (t < 64) {
        float sum = 0.f;
#pragma unroll
        for (int s = 0; s < 4; ++s)
            sum += lpart[(size_t)(s * 16 + p) * N_DIM + n0 + t];
        linv[t] = 1.f / sum;
    }

    const int d  = t >> 3;
    const int n8 = (t & 7) * 8;
    float a[8];
#pragma unroll
    for (int j = 0; j < 8; ++j) a[j] = 0.f;
#pragma unroll
    for (int s = 0; s < 4; ++s) {
        const size_t rb = ((size_t)(s * 16 + p) * 32 + d) * N_DIM + n0 + n8;
        ushort4 u0 = *(const ushort4*)&Opart[rb];
        ushort4 u1 = *(const ushort4*)&Opart[rb + 4];
        a[0] += bf16_to_f32(u0.x); a[1] += bf16_to_f32(u0.y);
        a[2] += bf16_to_f32(u0.z); a[3] += bf16_to_f32(u0.w);
        a[4] += bf16_to_f32(u1.x); a[5] += bf16_to_f32(u1.y);
        a[6] += bf16_to_f32(u1.z); a[7] += bf16_to_f32(u1.w);
    }
    __syncthreads();
#pragma unroll
    for (int j = 0; j < 8; ++j)
        Ts[n8 + j][d] = f32_to_bf16(a[j] * linv[n8 + j]);
    __syncthreads();
    const int dq = (t & 7) * 4;
    const int nr = t >> 3;
#pragma unroll
    for (int p2 = 0; p2 < 2; ++p2) {
        const int n = nr + p2 * 32;
        const int c = hh * 32 + dq;
        ushort4 u = *(const ushort4*)&Ts[n][dq];
        *(ushort4*)&AOt[(size_t)bb * N_DIM * C_DIM + SWZ(n0 + n, c)] = u;
    }
}

// ---------------------------------------------------------------------------
// Out projection: block = one 32o x 32n tile, 4 waves split K=256 (64 each),
// LDS reduce; fused bias + residual, fp32 out. All frag loads coalesced.
// ---------------------------------------------------------------------------
__global__ __launch_bounds__(256) void out_gemm(
    const short* __restrict__ OWsw, const short* __restrict__ AOt,
    const float* __restrict__ ob, const float* __restrict__ query,
    float* __restrict__ y)
{
    const int t = threadIdx.x, w = t >> 6, lane = t & 63;
    const int q2 = lane >> 5, l31 = lane & 31;
    const int n0 = blockIdx.x * 32, o0 = blockIdx.y * 32, b = blockIdx.z;
    const short* B = AOt + (size_t)b * N_DIM * C_DIM;
    const int abase = (o0 >> 5) * 8192 + q2 * 256 + l31 * 8;
    const int bbase = (n0 >> 5) * 8192 + q2 * 256 + l31 * 8;

    f32x16 acc;
#pragma unroll
    for (int r = 0; r < 16; ++r) acc[r] = 0.f;

    const int kc0 = w * 64;
#pragma unroll
    for (int s2 = 0; s2 < 4; ++s2) {
        const int kc = kc0 + s2 * 16;
        bf16x8 af = *(const bf16x8*)&OWsw[abase + (kc >> 4) * 512];
        bf16x8 bf = *(const bf16x8*)&B[bbase + (kc >> 4) * 512];
        acc = __builtin_amdgcn_mfma_f32_32x32x16_bf16(af, bf, acc, 0, 0, 0);
    }

    __shared__ float red[3][64][17];
    if (w > 0) {
#pragma unroll
        for (int r = 0; r < 16; ++r) red[w - 1][lane][r] = acc[r];
    }
    __syncthreads();
    if (w == 0) {
#pragma unroll
        for (int r = 0; r < 16; ++r)
            acc[r] += red[0][lane][r] + red[1][lane][r] + red[2][lane][r];
        const size_t base = (size_t)b * C_DIM * N_DIM;
#pragma unroll
        for (int r = 0; r < 16; ++r) {
            const int o = o0 + (r & 3) + 8 * (r >> 2) + 4 * q2;
            const int n = n0 + l31;
            const size_t addr = base + (size_t)o * N_DIM + n;
            y[addr] = acc[r] + ob[o] + query[addr];
        }
    }
}

// ---------------------------------------------------------------------------
// In-place GroupNorm over [B, C, N]: group g = channels 8g..8g+8.
// ---------------------------------------------------------------------------
__global__ __launch_bounds__(256) void groupnorm_kernel(
    float* __restrict__ data, const float* __restrict__ gw,
    const float* __restrict__ gb)
{
    const int g = blockIdx.x;
    const int b = blockIdx.y;
    const size_t base = ((size_t)b * C_DIM + (size_t)g * 8) * N_DIM;
    float4* Y4 = (float4*)(data + base);
    const int t = threadIdx.x;

    float sum = 0.f, sumsq = 0.f;
    for (int i = t; i < 8192; i += 256) {
        float4 v = Y4[i];
        sum   += v.x + v.y + v.z + v.w;
        sumsq += v.x * v.x + v.y * v.y + v.z * v.z + v.w * v.w;
    }
#pragma unroll
    for (int off = 1; off < 64; off <<= 1) {
        sum   += __shfl_xor(sum, off, 64);
        sumsq += __shfl_xor(sumsq, off, 64);
    }
    __shared__ float red[10];
    const int wid = t >> 6;
    if ((t & 63) == 0) { red[wid] = sum; red[4 + wid] = sumsq; }
    __syncthreads();
    if (t == 0) {
        float s = red[0] + red[1] + red[2] + red[3];
        float qq = red[4] + red[5] + red[6] + red[7];
        float mean = s * (1.f / 32768.f);
        float var  = qq * (1.f / 32768.f) - mean * mean;
        red[8] = mean;
        red[9] = rsqrtf(var + 1e-5f);
    }
    __syncthreads();
    const float mean = red[8], rstd = red[9];
    for (int i = t; i < 8192; i += 256) {
        const int c = i >> 10;
        const float wv  = gw[g * 8 + c] * rstd;
        const float bb2 = gb[g * 8 + c];
        float4 v = Y4[i];
        float4 r;
        r.x = (v.x - mean) * wv + bb2;
        r.y = (v.y - mean) * wv + bb2;
        r.z = (v.z - mean) * wv + bb2;
        r.w = (v.w - mean) * wv + bb2;
        Y4[i] = r;
    }
}

// ---------------------------------------------------------------------------
extern "C" void kernel_launch(void* const* d_in, const int* in_sizes, int n_in,
                              void* d_out, int out_size, void* d_ws, size_t ws_size,
                              hipStream_t stream)
{
    const float* query = (const float*)d_in[0];
    const float* key   = (const float*)d_in[1];
    const float* q_w   = (const float*)d_in[2];
    const float* q_b   = (const float*)d_in[3];
    const float* k_w   = (const float*)d_in[4];
    const float* k_b   = (const float*)d_in[5];
    const float* v_w   = (const float*)d_in[6];
    const float* v_b   = (const float*)d_in[7];
    const float* o_w   = (const float*)d_in[8];
    const float* o_b   = (const float*)d_in[9];
    const float* gn_w  = (const float*)d_in[10];
    const float* gn_b  = (const float*)d_in[11];

    // ws (MiB): [0,0.5) Wsw  [1,5) Qx (AOt aliases after projections)
    // [5,9) Kx  [9,13) Qt  [13,17) Kt  [17,21) Vt  [21,37) Opart  [37,38) lpart
    char* wsb = (char*)d_ws;
    short* Wsw   = (short*)wsb;
    short* Qx    = (short*)(wsb + (1u  << 20));
    short* Kx    = (short*)(wsb + (5u  << 20));
    short* Qt    = (short*)(wsb + (9u  << 20));
    short* Kt    = (short*)(wsb + (13u << 20));
    short* Vt    = (short*)(wsb + (17u << 20));
    short* Opart = (short*)(wsb + (21u << 20));
    float* lpart = (float*)(wsb + (37u << 20));
    short* AOt   = Qx;            // Qx dead after qkv_gemm
    float* y     = (float*)d_out; // in-place GroupNorm

    // softmax scale 1/sqrt(32) * log2(e), folded into Q projection
    const float qscale = 0.17677669529663687f * 1.4426950408889634f;

    prep<<<dim3(64, 4, 5), 256, 0, stream>>>(query, key, q_w, k_w, v_w, o_w,
                                             Qx, Kx, Wsw);
    qkv_gemm<<<dim3(64, 4, 6), 256, 0, stream>>>(Wsw, Qx, Kx, q_b, k_b, v_b,
                                                 Qt, Kt, Vt, qscale);
    flash_mfma<<<dim3(32, 8, 8), 256, 0, stream>>>(Qt, Kt, Vt, Opart, lpart);
    combine4<<<dim3(64, 16), 256, 0, stream>>>(Opart, lpart, AOt);
    out_gemm<<<dim3(128, 8, 2), 256, 0, stream>>>(Wsw + 3 * 65536, AOt, o_b,
                                                  query, y);
    groupnorm_kernel<<<dim3(32, 2), 256, 0, stream>>>(y, gn_w, gn_b);
}